// Round 7
// baseline (5453.786 us; speedup 1.0000x reference)
//
// MANN/NTM forward — R16: R9 structure + j-split TLP (NOT k-split).
// R12/R14/R15 lesson: any k-split of the weight GEMVs => GB-scale FETCH
// (multiple streaming fronts per block thrash per-XCD L2); rotation alone
// recovers only 20%. R9's full-k-chain-per-lane + rotated chunk order is the
// L2-resident regime (50MB FETCH). Here we keep that structure EXACTLY and
// double wave-parallelism by halving j-granularity: P2 = 400 lanes x float2,
// full k=200 (was 200 x float4); P4 = 324 lanes (162 j2 x 2 kh, as R9);
// P1 = 400 lanes (100 j2 x 4 kh). PIPE4 float2 buffers = 64 VGPR (was 128,
// which collapsed) so the 3-deep pipeline can materialize.
#include <hip/hip_runtime.h>
#include <math.h>

#define TB   100
#define BB   256
#define INF_ 784
#define HH   200
#define RR   4
#define NN   128
#define DD   40
#define NCLS 5
#define G4H  800   // 4*H
#define KAW  324   // 160 key + 160 add + 1 sigma + 3 pad
#define MST  44    // padded M row stride
#define NBAT 2     // batches per block
#define NBLK (BB / NBAT)

__device__ __forceinline__ float sigmoidf_(float x) { return 1.0f / (1.0f + expf(-x)); }

#define ADV(c, CC) { ++(c); if ((c) == (CC)) (c) = 0; }

// 4-slot rotating software pipeline (3 chunks of loads in flight ahead of FMA).
#define PIPE4(CC, OFS, LOADM, FMAM)                                     \
  {                                                                     \
    int chL = (OFS), chF = (OFS);                                       \
    LOADM(w0, chL); ADV(chL, CC); LOADM(w1, chL); ADV(chL, CC);         \
    LOADM(w2, chL); ADV(chL, CC);                                       \
    _Pragma("unroll 1")                                                 \
    for (int g = 0; g < ((CC) - 3) / 4; ++g) {                          \
      LOADM(w3, chL); ADV(chL, CC); FMAM(w0, chF); ADV(chF, CC);        \
      LOADM(w0, chL); ADV(chL, CC); FMAM(w1, chF); ADV(chF, CC);        \
      LOADM(w1, chL); ADV(chL, CC); FMAM(w2, chF); ADV(chF, CC);        \
      LOADM(w2, chL); ADV(chL, CC); FMAM(w3, chF); ADV(chF, CC);        \
    }                                                                   \
    {                                                                   \
      constexpr int REMX = (CC) - 3 - 4 * (((CC) - 3) / 4);             \
      if (REMX >= 1) { LOADM(w3, chL); ADV(chL, CC); }                  \
      FMAM(w0, chF); ADV(chF, CC);                                      \
      if (REMX >= 2) { LOADM(w0, chL); ADV(chL, CC); }                  \
      FMAM(w1, chF); ADV(chF, CC);                                      \
      if (REMX >= 3) { LOADM(w1, chL); ADV(chL, CC); }                  \
      FMAM(w2, chF); ADV(chF, CC);                                      \
      if (REMX >= 1) { FMAM(w3, chF); ADV(chF, CC); }                   \
      if (REMX >= 2) { FMAM(w0, chF); ADV(chF, CC); }                   \
      if (REMX >= 3) { FMAM(w1, chF); ADV(chF, CC); }                   \
    }                                                                   \
  }

// ---------------------------------------------------------------------------
// Prep: transpose weights into GEMV-friendly (k-major) layouts in workspace.
// ---------------------------------------------------------------------------
__global__ __launch_bounds__(256) void prep_kernel(
    const float* __restrict__ Whh, const float* __restrict__ Wrh,
    const float* __restrict__ Wkey, const float* __restrict__ Wadd,
    const float* __restrict__ Wsig, const float* __restrict__ bkey,
    const float* __restrict__ badd, const float* __restrict__ bsig,
    float* __restrict__ WhhT, float* __restrict__ WrhT,
    float* __restrict__ WkaT, float* __restrict__ bka)
{
  const int tid = blockIdx.x * 256 + threadIdx.x;
  if (tid < 160000) {            // Whh (800,200) -> WhhT (200,800)
    const int j = tid / 200, k = tid - j * 200;
    WhhT[k * G4H + j] = Whh[tid];
  }
  if (tid < 32000) {             // Wrh (200,160) -> WrhT (160,200)
    const int k = tid / 160, m = tid - k * 160;
    WrhT[m * HH + k] = Wrh[tid];
  }
  if (tid < 200 * KAW) {         // [Wkey(160,200)|Wadd(160,200)|Wsig(1,200)]^T
    const int k = tid / KAW, j = tid - k * KAW;
    float v = 0.0f;
    if (j < 160)       v = Wkey[j * HH + k];
    else if (j < 320)  v = Wadd[(j - 160) * HH + k];
    else if (j == 320) v = Wsig[k];
    WkaT[tid] = v;
  }
  if (tid < KAW) {
    float v = 0.0f;
    if (tid < 160)       v = bkey[tid];
    else if (tid < 320)  v = badd[tid - 160];
    else if (tid == 320) v = bsig[0];
    bka[tid] = v;
  }
}

// ---------------------------------------------------------------------------
// Big GEMM: G[m, j] = sum_k x[m,k]*Wih[j,k] + bih[j] + bhh[j]
// ---------------------------------------------------------------------------
__global__ __launch_bounds__(256) void gemm_in_kernel(
    const float* __restrict__ X, const float* __restrict__ Wih,
    const float* __restrict__ bih, const float* __restrict__ bhh,
    float* __restrict__ G)
{
  __shared__ float As[16 * 68];
  __shared__ float Bs[16 * 68];
  const int tid  = threadIdx.x;
  const int tx   = tid & 15, ty = tid >> 4;
  const int lrow = tid >> 2, lk = (tid & 3) * 4;
  const int n0 = blockIdx.x * 64;
  const int m0 = blockIdx.y * 64;
  const int jg = n0 + lrow;
  const float* Xp = X   + (size_t)(m0 + lrow) * INF_ + lk;
  const float* Wp = Wih + (size_t)jg * INF_ + lk;

  float acc[4][4];
#pragma unroll
  for (int i = 0; i < 4; ++i)
#pragma unroll
    for (int j = 0; j < 4; ++j) acc[i][j] = 0.f;

  for (int k0 = 0; k0 < INF_; k0 += 16) {
    const float4 a = *(const float4*)(Xp + k0);
    const float4 b = (jg < G4H) ? *(const float4*)(Wp + k0)
                                : make_float4(0.f, 0.f, 0.f, 0.f);
    __syncthreads();
    const float av[4] = {a.x, a.y, a.z, a.w};
    const float bv[4] = {b.x, b.y, b.z, b.w};
#pragma unroll
    for (int u = 0; u < 4; ++u) {
      As[(lk + u) * 68 + lrow] = av[u];
      Bs[(lk + u) * 68 + lrow] = bv[u];
    }
    __syncthreads();
#pragma unroll
    for (int k = 0; k < 16; ++k) {
      const float4 a4 = *(const float4*)&As[k * 68 + ty * 4];
      const float4 b4 = *(const float4*)&Bs[k * 68 + tx * 4];
      const float aa[4] = {a4.x, a4.y, a4.z, a4.w};
      const float bb[4] = {b4.x, b4.y, b4.z, b4.w};
#pragma unroll
      for (int i = 0; i < 4; ++i)
#pragma unroll
        for (int j = 0; j < 4; ++j) acc[i][j] += aa[i] * bb[j];
    }
  }
  const int jc = n0 + tx * 4;
  if (jc < G4H) {
    float bs[4];
#pragma unroll
    for (int u = 0; u < 4; ++u) bs[u] = bih[jc + u] + bhh[jc + u];
#pragma unroll
    for (int i = 0; i < 4; ++i) {
      const size_t m = (size_t)m0 + ty * 4 + i;
      const float4 v = make_float4(acc[i][0] + bs[0], acc[i][1] + bs[1],
                                   acc[i][2] + bs[2], acc[i][3] + bs[3]);
      *(float4*)(G + m * G4H + jc) = v;
    }
  }
}

// ---------------------------------------------------------------------------
// Recurrence: one block (512 thr) per 2 batch elements; 128 blocks.
// j-split GEMVs: full-k chain per lane (L2-resident sweep), float2 outputs.
// ---------------------------------------------------------------------------
__global__ __launch_bounds__(512, 2) void mann_kernel(
    const float* __restrict__ G, const float* __restrict__ WhhT,
    const float* __restrict__ WrhT, const float* __restrict__ WkaT,
    const float* __restrict__ bka, const float* __restrict__ brh,
    const float* __restrict__ Who, const float* __restrict__ bho,
    const float* __restrict__ Wro, const float* __restrict__ bro,
    float* __restrict__ out)
{
  __shared__ __attribute__((aligned(16))) float M_s[NBAT][NN * MST];
  __shared__ __attribute__((aligned(16))) float h2[HH * NBAT];   // [k*2+i]
  __shared__ __attribute__((aligned(16))) float c2[HH * NBAT];
  __shared__ __attribute__((aligned(16))) float r2[RR * DD * NBAT];
  __shared__ __attribute__((aligned(16))) float brh_s[HH];
  __shared__ float wr_s[NBAT][RR * NN];
  __shared__ float ww_s[NBAT][RR * NN];
  __shared__ float wu_s[NBAT][NN];
  __shared__ float Mn2_s[NBAT][NN];
  __shared__ float kn2_s[NBAT][RR];
  __shared__ __attribute__((aligned(16))) float gates_s[NBAT][G4H];
  __shared__ __attribute__((aligned(16))) float ka_s[NBAT][KAW];
  __shared__ __attribute__((aligned(16))) float bka_s[KAW];
  __shared__ __attribute__((aligned(16))) float Gbuf_s[NBAT][G4H];
  __shared__ float Who_s[NCLS * HH], Wro_s[NCLS * RR * DD], bo_s[NCLS];
  __shared__ int   lu_s[NBAT][RR];

  // Aliases into the gates region (temporally disjoint):
  float*  Kp  = &gates_s[0][0];           // [2][512] wr_t (P8..P12)
  float2* pk1 = (float2*)&gates_s[0][0];  // P1 partials: 600 float2
  float2* pk4 = (float2*)&gates_s[0][0];  // P4 partials: 324 float2

  const int tid = threadIdx.x;
  const int b0  = blockIdx.x * NBAT;

  // ---- init ----
  for (int e = tid; e < NBAT * NN * MST; e += 512) (&M_s[0][0])[e] = 0.f;
  for (int e = tid; e < NBAT * RR * NN; e += 512) (&wr_s[0][0])[e] = 0.f;
  if (tid < NBAT * NN) (&wu_s[0][0])[tid] = 0.f;
  for (int e = tid; e < HH * NBAT; e += 512) { h2[e] = 0.f; c2[e] = 0.f; }
  if (tid < RR * DD * NBAT) r2[tid] = 0.f;
  if (tid < HH) brh_s[tid] = brh[tid];
  if (tid < KAW) bka_s[tid] = bka[tid];
  for (int e = tid; e < NCLS * HH; e += 512) Who_s[e] = Who[e];
  for (int e = tid; e < NCLS * RR * DD; e += 512) Wro_s[e] = Wro[e];
  if (tid < NCLS) bo_s[tid] = bho[tid] + bro[tid];
  if (tid < NBAT * 200) {
    const int i = tid / 200, o = tid - i * 200;
    ((float4*)&Gbuf_s[i][0])[o] =
        ((const float4*)(G + ((size_t)(b0 + i) * TB) * G4H))[o];
  }
  __syncthreads();

  const int ofs1 = (int)((blockIdx.x * 3u) % 5u);
  const int ofs2 = (int)((blockIdx.x * 7u) % 25u);
  const int ofs4 = (int)((blockIdx.x * 3u) % 10u);

#pragma clang loop unroll(disable)
  for (int t = 0; t < TB; ++t) {
    float2 p1a0 = make_float2(0.f, 0.f);
    float2 p1a1 = make_float2(0.f, 0.f);
    float2 p4a0 = make_float2(0.f, 0.f);
    float2 p4a1 = make_float2(0.f, 0.f);

    // ---- P1: h += r @ Wrh^T (400 lanes = 100 j2 x 4 kh, 40-k chains) ----
    if (tid < 400) {
      const int kh = tid / 100, j2 = tid - kh * 100;
      const int kbeg = kh * 40;
      const float2* __restrict__ Wr2 = (const float2*)WrhT + (size_t)kbeg * 100 + j2;
      float2 w0[8], w1[8], w2[8], w3[8];
#define P1_LOAD(B, CH) { const int mm = (CH) * 8; _Pragma("unroll") \
      for (int u = 0; u < 8; ++u) B[u] = Wr2[(mm + u) * 100]; }
#define P1_FMA(B, CH) { const int kb = kbeg + (CH) * 8; _Pragma("unroll") \
      for (int u = 0; u < 8; ++u) { const float2 rk = *(const float2*)&r2[(kb + u) * 2]; \
        p1a0.x += rk.x * B[u].x; p1a0.y += rk.x * B[u].y; \
        p1a1.x += rk.y * B[u].x; p1a1.y += rk.y * B[u].y; } }
      PIPE4(5, ofs1, P1_LOAD, P1_FMA)
      if (kh) { pk1[(kh - 1) * 100 + j2] = p1a0; pk1[300 + (kh - 1) * 100 + j2] = p1a1; }
    }
    __syncthreads();
    // ---- P1b: finalize h (100 lanes = the kh0 lanes, accs live in regs) ----
    if (tid < 100) {
      float2 s0 = p1a0, s1 = p1a1;
#pragma unroll
      for (int m = 0; m < 3; ++m) {
        const float2 q0 = pk1[m * 100 + tid];
        const float2 q1 = pk1[300 + m * 100 + tid];
        s0.x += q0.x; s0.y += q0.y; s1.x += q1.x; s1.y += q1.y;
      }
      const float b0v = brh_s[2 * tid], b1v = brh_s[2 * tid + 1];
      h2[4 * tid + 0] += s0.x + b0v;   // j=2t,   batch0
      h2[4 * tid + 1] += s1.x + b0v;   // j=2t,   batch1
      h2[4 * tid + 2] += s0.y + b1v;   // j=2t+1, batch0
      h2[4 * tid + 3] += s1.y + b1v;   // j=2t+1, batch1
    }
    __syncthreads();

    // ---- P2: gates = Gbuf + h @ Whh^T (400 lanes x float2, full k=200) ----
    if (tid < 400) {
      const float2* __restrict__ Wh2 = (const float2*)WhhT + tid;
      float2 g0 = make_float2(0.f, 0.f);
      float2 g1 = make_float2(0.f, 0.f);
      float2 w0[8], w1[8], w2[8], w3[8];
#define P2_LOAD(B, CH) { const int kk = (CH) * 8; _Pragma("unroll") \
      for (int u = 0; u < 8; ++u) B[u] = Wh2[(kk + u) * 400]; }
#define P2_FMA(B, CH) { const int kc = (CH) * 8; _Pragma("unroll") \
      for (int u = 0; u < 8; ++u) { const float2 hk = *(const float2*)&h2[(kc + u) * 2]; \
        g0.x += hk.x * B[u].x; g0.y += hk.x * B[u].y; \
        g1.x += hk.y * B[u].x; g1.y += hk.y * B[u].y; } }
      PIPE4(25, ofs2, P2_LOAD, P2_FMA)
      const float2 gb0 = *(const float2*)&Gbuf_s[0][2 * tid];
      const float2 gb1 = *(const float2*)&Gbuf_s[1][2 * tid];
      *(float2*)&gates_s[0][2 * tid] = make_float2(gb0.x + g0.x, gb0.y + g0.y);
      *(float2*)&gates_s[1][2 * tid] = make_float2(gb1.x + g1.x, gb1.y + g1.y);
    }
    __syncthreads();

    // ---- P3: LSTM pointwise (400 items) ----
    if (tid < NBAT * HH) {
      const int i = tid / HH, k = tid - i * HH;
      const float ig = sigmoidf_(gates_s[i][k]);
      const float fg = sigmoidf_(gates_s[i][HH + k]);
      const float gg = tanhf(gates_s[i][2 * HH + k]);
      const float og = sigmoidf_(gates_s[i][3 * HH + k]);
      const float cn = fg * c2[k * NBAT + i] + ig * gg;
      c2[k * NBAT + i] = cn;
      h2[k * NBAT + i] = og * tanhf(cn);
    }
    __syncthreads();

    // ---- P4: [key|add|sigma] = bka + h @ Wka^T (324 lanes = 162 j2 x 2 kh);
    //      lanes>=384 prefetch G(t+1) ----
    if (tid < 324) {
      const int kh = tid / 162, j2 = tid - kh * 162;
      const int kbeg = kh * 100;
      const float2* __restrict__ Wk2 = (const float2*)WkaT + (size_t)kbeg * 162 + j2;
      float2 w0[10], w1[10], w2[10], w3[10];
#define P4_LOAD(B, CH) { const int kk = (CH) * 10; _Pragma("unroll") \
      for (int u = 0; u < 10; ++u) B[u] = Wk2[(kk + u) * 162]; }
#define P4_FMA(B, CH) { const int kc = kbeg + (CH) * 10; _Pragma("unroll") \
      for (int u = 0; u < 10; ++u) { const float2 hk = *(const float2*)&h2[(kc + u) * 2]; \
        p4a0.x += hk.x * B[u].x; p4a0.y += hk.x * B[u].y; \
        p4a1.x += hk.y * B[u].x; p4a1.y += hk.y * B[u].y; } }
      PIPE4(10, ofs4, P4_LOAD, P4_FMA)
      if (kh) { pk4[j2] = p4a0; pk4[162 + j2] = p4a1; }
    } else if (tid >= 384 && t + 1 < TB) {
      for (int idx = tid - 384; idx < NBAT * 200; idx += 128) {
        const int i = idx / 200, o = idx - i * 200;
        ((float4*)&Gbuf_s[i][0])[o] =
            ((const float4*)(G + ((size_t)(b0 + i) * TB + t + 1) * G4H))[o];
      }
    }
    __syncthreads();
    // ---- P4b: finalize ka (162 lanes = the kh0 lanes) ----
    if (tid < 162) {
      const float2 bb = *(const float2*)&bka_s[2 * tid];
      const float2 q0 = pk4[tid], q1 = pk4[162 + tid];
      *(float2*)&ka_s[0][2 * tid] =
          make_float2(p4a0.x + q0.x + bb.x, p4a0.y + q0.y + bb.y);
      *(float2*)&ka_s[1][2 * tid] =
          make_float2(p4a1.x + q1.x + bb.x, p4a1.y + q1.y + bb.y);
    }
    __syncthreads();

    // ---- P5: least-used select (waves 0-1, one per batch) + key norms ----
    if (tid < NBAT * 64) {
      const int i = tid >> 6, l = tid & 63;
      unsigned u0v = __float_as_uint(wu_s[i][l]);
      unsigned u1v = __float_as_uint(wu_s[i][l + 64]);
      if (u0v == 0x80000000u) u0v = 0u;
      if (u1v == 0x80000000u) u1v = 0u;
      u0v = (u0v & 0x80000000u) ? ~u0v : (u0v | 0x80000000u);
      u1v = (u1v & 0x80000000u) ? ~u1v : (u1v | 0x80000000u);
      unsigned long long k0 = ((unsigned long long)u0v << 32) | (unsigned)l;
      unsigned long long k1 = ((unsigned long long)u1v << 32) | (unsigned)(l + 64);
#pragma unroll
      for (int rsel = 0; rsel < RR; ++rsel) {
        unsigned long long mn = (k0 < k1) ? k0 : k1;
#pragma unroll
        for (int off = 32; off; off >>= 1) {
          const unsigned long long o = __shfl_xor(mn, off);
          if (o < mn) mn = o;
        }
        const int idx = (int)(mn & 0xFFFFFFFFull);
        if (l == 0) lu_s[i][rsel] = idx;
        if (idx == l)      k0 = ~0ull;
        if (idx == l + 64) k1 = ~0ull;
      }
    } else if (tid < NBAT * 64 + NBAT * RR) {
      const int e = tid - NBAT * 64;
      const int i = e >> 2, q = e & 3;
      float s = 0.f;
#pragma unroll
      for (int d4 = 0; d4 < 10; ++d4) {
        const float4 v = *(const float4*)&ka_s[i][q * DD + 4 * d4];
        s += v.x * v.x + v.y * v.y + v.z * v.z + v.w * v.w;
      }
      kn2_s[i][q] = s;
    }
    __syncthreads();

    // ---- P6: ww = sigma*wr + (1-sigma)*wlu ----
    {
      const int n = tid & (NN - 1);
#pragma unroll
      for (int i = 0; i < NBAT; ++i) {
        const float sg = ka_s[i][320];
        const int l0 = lu_s[i][0], l1 = lu_s[i][1], l2 = lu_s[i][2], l3 = lu_s[i][3];
        const float wlu = (n == l0 || n == l1 || n == l2 || n == l3) ? 1.f : 0.f;
        ww_s[i][tid] = sg * wr_s[i][tid] + (1.f - sg) * wlu;
      }
    }
    __syncthreads();

    // ---- P7: M = M*wlu + ww^T @ add ; fused row-norm (256 lanes: i,n) ----
    if (tid < NBAT * NN) {
      const int i = tid >> 7, n = tid & (NN - 1);
      const int l0 = lu_s[i][0], l1 = lu_s[i][1], l2 = lu_s[i][2], l3 = lu_s[i][3];
      const float wlu = (n == l0 || n == l1 || n == l2 || n == l3) ? 1.f : 0.f;
      const float wwv0 = ww_s[i][n],          wwv1 = ww_s[i][NN + n];
      const float wwv2 = ww_s[i][2 * NN + n], wwv3 = ww_s[i][3 * NN + n];
      float* Mr = &M_s[i][n * MST];
      const float* Ad = &ka_s[i][160];
      float mn2 = 0.f;
#pragma unroll
      for (int d4 = 0; d4 < 10; ++d4) {
        float4 m = *(const float4*)&Mr[4 * d4];
        m.x *= wlu; m.y *= wlu; m.z *= wlu; m.w *= wlu;
        const float4 av0 = *(const float4*)&Ad[0 * DD + 4 * d4];
        const float4 av1 = *(const float4*)&Ad[1 * DD + 4 * d4];
        const float4 av2 = *(const float4*)&Ad[2 * DD + 4 * d4];
        const float4 av3 = *(const float4*)&Ad[3 * DD + 4 * d4];
        m.x += wwv0 * av0.x + wwv1 * av1.x + wwv2 * av2.x + wwv3 * av3.x;
        m.y += wwv0 * av0.y + wwv1 * av1.y + wwv2 * av2.y + wwv3 * av3.y;
        m.z += wwv0 * av0.z + wwv1 * av1.z + wwv2 * av2.z + wwv3 * av3.z;
        m.w += wwv0 * av0.w + wwv1 * av1.w + wwv2 * av2.w + wwv3 * av3.w;
        *(float4*)&Mr[4 * d4] = m;
        mn2 += m.x * m.x + m.y * m.y + m.z * m.z + m.w * m.w;
      }
      Mn2_s[i][n] = mn2;
    }
    __syncthreads();

    // ---- P8: K = cosine(key, M): 512 lanes, each reads one M row, 2 keys ----
    {
      const int i = tid >> 8, qq = (tid >> 7) & 1, n = tid & (NN - 1);
      const float* Mr = &M_s[i][n * MST];
      const float* Ky0 = &ka_s[i][qq * DD];
      const float* Ky1 = &ka_s[i][(qq + 2) * DD];
      float s0 = 0.f, s1 = 0.f;
#pragma unroll
      for (int d4 = 0; d4 < 10; ++d4) {
        const float4 mv = *(const float4*)&Mr[4 * d4];
        const float4 k0v = *(const float4*)&Ky0[4 * d4];
        const float4 k1v = *(const float4*)&Ky1[4 * d4];
        s0 += k0v.x * mv.x + k0v.y * mv.y + k0v.z * mv.z + k0v.w * mv.w;
        s1 += k1v.x * mv.x + k1v.y * mv.y + k1v.z * mv.z + k1v.w * mv.w;
      }
      const float mn2 = Mn2_s[i][n];
      Kp[(i << 9) + qq * NN + n]       = s0 / sqrtf(kn2_s[i][qq] * mn2 + 1e-6f);
      Kp[(i << 9) + (qq + 2) * NN + n] = s1 / sqrtf(kn2_s[i][qq + 2] * mn2 + 1e-6f);
    }
    __syncthreads();

    // ---- P9: softmax over N (8 rows, one per wave) ----
    {
      const int w = tid >> 6, l = tid & 63;
      float* Kr = Kp + ((w >> 2) << 9) + (w & 3) * NN;
      const float v0 = Kr[l], v1 = Kr[l + 64];
      float mx = fmaxf(v0, v1);
#pragma unroll
      for (int off = 32; off; off >>= 1) mx = fmaxf(mx, __shfl_xor(mx, off));
      const float e0 = expf(v0 - mx), e1 = expf(v1 - mx);
      float s = e0 + e1;
#pragma unroll
      for (int off = 32; off; off >>= 1) s += __shfl_xor(s, off);
      const float inv = 1.f / s;
      Kr[l] = e0 * inv; Kr[l + 64] = e1 * inv;
    }
    __syncthreads();

    // ---- P10: r = wr_t @ M (80 lanes, broadcast) ; P11: wu (lanes 256+) ----
    if (tid < NBAT * RR * 10) {
      const int i = tid / (RR * 10), rem = tid - i * (RR * 10);
      const int q = rem / 10, d4 = rem - q * 10;
      const float* Kr = Kp + (i << 9) + q * NN;
      const float* Mb = &M_s[i][4 * d4];
      float4 acc = make_float4(0.f, 0.f, 0.f, 0.f);
      for (int n = 0; n < NN; ++n) {
        const float kw = Kr[n];
        const float4 mv = *(const float4*)&Mb[n * MST];
        acc.x += kw * mv.x; acc.y += kw * mv.y;
        acc.z += kw * mv.z; acc.w += kw * mv.w;
      }
      const int dbase = (q * DD + 4 * d4) * NBAT + i;
      r2[dbase]            = acc.x;
      r2[dbase + NBAT]     = acc.y;
      r2[dbase + 2 * NBAT] = acc.z;
      r2[dbase + 3 * NBAT] = acc.w;
    } else if (tid >= 256 && tid < 256 + NBAT * NN) {
      const int e = tid - 256;
      const int i = e >> 7, n = e & (NN - 1);
      float s = 0.95f * wu_s[i][n];
#pragma unroll
      for (int q = 0; q < RR; ++q)
        s += Kp[(i << 9) + q * NN + n] + ww_s[i][q * NN + n];
      wu_s[i][n] = s;
    }
    __syncthreads();

    // ---- P12: out (waves 0-1) ; wr <- wr_t (waves 4-7) ----
    if (tid < NBAT * 64) {
      const int i = tid >> 6, l = tid & 63;
      const size_t ob = ((size_t)(b0 + i) * TB + t) * NCLS;
#pragma unroll
      for (int j = 0; j < NCLS; ++j) {
        float p = 0.f;
        for (int k = l; k < HH; k += 64)      p += h2[k * NBAT + i] * Who_s[j * HH + k];
        for (int m = l; m < RR * DD; m += 64) p += r2[m * NBAT + i] * Wro_s[j * RR * DD + m];
#pragma unroll
        for (int off = 32; off; off >>= 1) p += __shfl_xor(p, off);
        if (l == 0) out[ob + j] = p + bo_s[j];
      }
    } else if (tid >= 256) {
      for (int f = tid - 256; f < NBAT * RR * NN; f += 256) (&wr_s[0][0])[f] = Kp[f];
    }
    __syncthreads();
  }
}

// ---------------------------------------------------------------------------
extern "C" void kernel_launch(void* const* d_in, const int* in_sizes, int n_in,
                              void* d_out, int out_size, void* d_ws, size_t ws_size,
                              hipStream_t stream) {
  const float* x    = (const float*)d_in[0];
  const float* Wkey = (const float*)d_in[1];
  const float* bkey = (const float*)d_in[2];
  const float* Wadd = (const float*)d_in[3];
  const float* badd = (const float*)d_in[4];
  const float* Wsig = (const float*)d_in[5];
  const float* bsig = (const float*)d_in[6];
  const float* Who  = (const float*)d_in[7];
  const float* bho  = (const float*)d_in[8];
  const float* Wro  = (const float*)d_in[9];
  const float* bro  = (const float*)d_in[10];
  const float* Wrh  = (const float*)d_in[11];
  const float* brh  = (const float*)d_in[12];
  const float* Wih  = (const float*)d_in[13];
  const float* bih  = (const float*)d_in[14];
  const float* Whh  = (const float*)d_in[15];
  const float* bhh  = (const float*)d_in[16];

  float* ws   = (float*)d_ws;
  float* G    = ws;                       // 25600*800
  float* WhhT = G + (size_t)25600 * 800;  // 160,000
  float* WrhT = WhhT + 160000;            // 32,000
  float* WkaT = WrhT + 32000;             // 64,800
  float* bka  = WkaT + 64800;             // 324

  prep_kernel<<<(160000 + 255) / 256, 256, 0, stream>>>(
      Whh, Wrh, Wkey, Wadd, Wsig, bkey, badd, bsig, WhhT, WrhT, WkaT, bka);

  dim3 gA((G4H + 63) / 64, 25600 / 64);
  gemm_in_kernel<<<gA, 256, 0, stream>>>(x, Wih, bih, bhh, G);

  mann_kernel<<<NBLK, 512, 0, stream>>>(G, WhhT, WrhT, WkaT, bka, brh,
                                        Who, bho, Wro, bro, (float*)d_out);
}

// Round 8
// 2889.999 us; speedup vs baseline: 1.8871x; 1.8871x over previous
//
// MANN/NTM forward — R17: mann frozen at R9 (3173µs, 50MB-FETCH regime —
// rounds 11-16 proved ANY GEMV lane-geometry change explodes FETCH).
// New: gemm_in replaced with split-precision bf16 MFMA GEMM
// (G = xhi·Whi^T + xlo·Whi^T + xhi·Wlo^T, rel err ~2^-16 ≈ fp32).
// gemm was ~475µs fp32-vector; MFMA path ~60-120µs.
#include <hip/hip_runtime.h>
#include <math.h>

#define TB   100
#define BB   256
#define INF_ 784
#define HH   200
#define RR   4
#define NN   128
#define DD   40
#define NCLS 5
#define G4H  800   // 4*H
#define KAW  324   // 160 key + 160 add + 1 sigma + 3 pad
#define MST  44    // padded M row stride
#define NBAT 2     // batches per block
#define NBLK (BB / NBAT)

typedef __attribute__((ext_vector_type(8))) short bf16x8;
typedef __attribute__((ext_vector_type(4))) float f32x4;

__device__ __forceinline__ float sigmoidf_(float x) { return 1.0f / (1.0f + expf(-x)); }

__device__ __forceinline__ void splitbf_(float v, unsigned short &hi, unsigned short &lo) {
  const unsigned b = __float_as_uint(v);
  hi = (unsigned short)(b >> 16);
  const float hf = __uint_as_float(b & 0xFFFF0000u);
  lo = (unsigned short)(__float_as_uint(v - hf) >> 16);
}

#define ADV(c, CC) { ++(c); if ((c) == (CC)) (c) = 0; }

// 4-slot rotating software pipeline (3 chunks of loads in flight ahead of FMA).
#define PIPE4(CC, OFS, LOADM, FMAM)                                     \
  {                                                                     \
    int chL = (OFS), chF = (OFS);                                       \
    LOADM(w0, chL); ADV(chL, CC); LOADM(w1, chL); ADV(chL, CC);         \
    LOADM(w2, chL); ADV(chL, CC);                                       \
    _Pragma("unroll 1")                                                 \
    for (int g = 0; g < ((CC) - 3) / 4; ++g) {                          \
      LOADM(w3, chL); ADV(chL, CC); FMAM(w0, chF); ADV(chF, CC);        \
      LOADM(w0, chL); ADV(chL, CC); FMAM(w1, chF); ADV(chF, CC);        \
      LOADM(w1, chL); ADV(chL, CC); FMAM(w2, chF); ADV(chF, CC);        \
      LOADM(w2, chL); ADV(chL, CC); FMAM(w3, chF); ADV(chF, CC);        \
    }                                                                   \
    {                                                                   \
      constexpr int REMX = (CC) - 3 - 4 * (((CC) - 3) / 4);             \
      if (REMX >= 1) { LOADM(w3, chL); ADV(chL, CC); }                  \
      FMAM(w0, chF); ADV(chF, CC);                                      \
      if (REMX >= 2) { LOADM(w0, chL); ADV(chL, CC); }                  \
      FMAM(w1, chF); ADV(chF, CC);                                      \
      if (REMX >= 3) { LOADM(w1, chL); ADV(chL, CC); }                  \
      FMAM(w2, chF); ADV(chF, CC);                                      \
      if (REMX >= 1) { FMAM(w3, chF); ADV(chF, CC); }                   \
      if (REMX >= 2) { FMAM(w0, chF); ADV(chF, CC); }                   \
      if (REMX >= 3) { FMAM(w1, chF); ADV(chF, CC); }                   \
    }                                                                   \
  }

// ---------------------------------------------------------------------------
// Prep: transpose weights into GEMV-friendly (k-major) layouts in workspace.
// ---------------------------------------------------------------------------
__global__ __launch_bounds__(256) void prep_kernel(
    const float* __restrict__ Whh, const float* __restrict__ Wrh,
    const float* __restrict__ Wkey, const float* __restrict__ Wadd,
    const float* __restrict__ Wsig, const float* __restrict__ bkey,
    const float* __restrict__ badd, const float* __restrict__ bsig,
    float* __restrict__ WhhT, float* __restrict__ WrhT,
    float* __restrict__ WkaT, float* __restrict__ bka)
{
  const int tid = blockIdx.x * 256 + threadIdx.x;
  if (tid < 160000) {            // Whh (800,200) -> WhhT (200,800)
    const int j = tid / 200, k = tid - j * 200;
    WhhT[k * G4H + j] = Whh[tid];
  }
  if (tid < 32000) {             // Wrh (200,160) -> WrhT (160,200)
    const int k = tid / 160, m = tid - k * 160;
    WrhT[m * HH + k] = Wrh[tid];
  }
  if (tid < 200 * KAW) {         // [Wkey(160,200)|Wadd(160,200)|Wsig(1,200)]^T
    const int k = tid / KAW, j = tid - k * KAW;
    float v = 0.0f;
    if (j < 160)       v = Wkey[j * HH + k];
    else if (j < 320)  v = Wadd[(j - 160) * HH + k];
    else if (j == 320) v = Wsig[k];
    WkaT[tid] = v;
  }
  if (tid < KAW) {
    float v = 0.0f;
    if (tid < 160)       v = bkey[tid];
    else if (tid < 320)  v = badd[tid - 160];
    else if (tid == 320) v = bsig[0];
    bka[tid] = v;
  }
}

// ---------------------------------------------------------------------------
// gemm_in2: G[m,j] = sum_k x[m,k]*Wih[j,k] + bih[j] + bhh[j]  (MFMA bf16,
// split-precision hi/lo). Tile 128(M) x 80(N), 256 thr = 4 waves, K-step 32.
// ---------------------------------------------------------------------------
#define GM  128
#define GN  80
#define LDK 40   // padded K stride in bf16 elems (80B, 16B-aligned rows)

__global__ __launch_bounds__(256) void gemm_in2_kernel(
    const float* __restrict__ X, const float* __restrict__ Wih,
    const float* __restrict__ bih, const float* __restrict__ bhh,
    float* __restrict__ G)
{
  __shared__ __attribute__((aligned(16))) unsigned short Ahi[GM][LDK];
  __shared__ __attribute__((aligned(16))) unsigned short Alo[GM][LDK];
  __shared__ __attribute__((aligned(16))) unsigned short Bhi[GN][LDK];
  __shared__ __attribute__((aligned(16))) unsigned short Blo[GN][LDK];

  const int tid  = threadIdx.x;
  const int wv   = tid >> 6, lane = tid & 63;
  const int n0   = blockIdx.x * GN;
  const int m0   = blockIdx.y * GM;

  f32x4 acc[2][5];
#pragma unroll
  for (int mt = 0; mt < 2; ++mt)
#pragma unroll
    for (int nt = 0; nt < 5; ++nt) acc[mt][nt] = (f32x4){0.f, 0.f, 0.f, 0.f};

  const int arow = tid >> 1, ak = (tid & 1) * 16;
  const float* Ap = X + (size_t)(m0 + arow) * INF_ + ak;
  const float* Bp = Wih + (size_t)(n0 + arow) * INF_ + ak;  // arow<80 when tid<160

  const int fr = lane & 15, fk = (lane >> 4) * 8;

  for (int kk = 0; kk < 800; kk += 32) {
    // ---- global loads (zero-padded past K=784; 784%16==0 so per-16 guard) ----
    float va[16], vb[16];
    const bool av = (kk + ak) < INF_;
#pragma unroll
    for (int i = 0; i < 16; ++i) va[i] = 0.f;
    if (av) {
      *(float4*)&va[0]  = *(const float4*)(Ap + kk);
      *(float4*)&va[4]  = *(const float4*)(Ap + kk + 4);
      *(float4*)&va[8]  = *(const float4*)(Ap + kk + 8);
      *(float4*)&va[12] = *(const float4*)(Ap + kk + 12);
    }
    if (tid < 160) {
#pragma unroll
      for (int i = 0; i < 16; ++i) vb[i] = 0.f;
      if (av) {
        *(float4*)&vb[0]  = *(const float4*)(Bp + kk);
        *(float4*)&vb[4]  = *(const float4*)(Bp + kk + 4);
        *(float4*)&vb[8]  = *(const float4*)(Bp + kk + 8);
        *(float4*)&vb[12] = *(const float4*)(Bp + kk + 12);
      }
    }
    __syncthreads();   // prior compute done before LDS overwrite
    // ---- convert + store to LDS ----
    {
      unsigned ah[8], al[8];
#pragma unroll
      for (int i = 0; i < 8; ++i) {
        unsigned short h0, l0, h1, l1;
        splitbf_(va[2 * i], h0, l0);
        splitbf_(va[2 * i + 1], h1, l1);
        ah[i] = (unsigned)h0 | ((unsigned)h1 << 16);
        al[i] = (unsigned)l0 | ((unsigned)l1 << 16);
      }
      ((int4*)&Ahi[arow][ak])[0] = make_int4(ah[0], ah[1], ah[2], ah[3]);
      ((int4*)&Ahi[arow][ak + 8])[0] = make_int4(ah[4], ah[5], ah[6], ah[7]);
      ((int4*)&Alo[arow][ak])[0] = make_int4(al[0], al[1], al[2], al[3]);
      ((int4*)&Alo[arow][ak + 8])[0] = make_int4(al[4], al[5], al[6], al[7]);
    }
    if (tid < 160) {
      unsigned bh[8], bl[8];
#pragma unroll
      for (int i = 0; i < 8; ++i) {
        unsigned short h0, l0, h1, l1;
        splitbf_(vb[2 * i], h0, l0);
        splitbf_(vb[2 * i + 1], h1, l1);
        bh[i] = (unsigned)h0 | ((unsigned)h1 << 16);
        bl[i] = (unsigned)l0 | ((unsigned)l1 << 16);
      }
      ((int4*)&Bhi[arow][ak])[0] = make_int4(bh[0], bh[1], bh[2], bh[3]);
      ((int4*)&Bhi[arow][ak + 8])[0] = make_int4(bh[4], bh[5], bh[6], bh[7]);
      ((int4*)&Blo[arow][ak])[0] = make_int4(bl[0], bl[1], bl[2], bl[3]);
      ((int4*)&Blo[arow][ak + 8])[0] = make_int4(bl[4], bl[5], bl[6], bl[7]);
    }
    __syncthreads();
    // ---- MFMA: 2 m-tiles x 5 n-tiles x 3 passes ----
    const bf16x8 a0h = *(const bf16x8*)&Ahi[wv * 32 + fr][fk];
    const bf16x8 a0l = *(const bf16x8*)&Alo[wv * 32 + fr][fk];
    const bf16x8 a1h = *(const bf16x8*)&Ahi[wv * 32 + 16 + fr][fk];
    const bf16x8 a1l = *(const bf16x8*)&Alo[wv * 32 + 16 + fr][fk];
#pragma unroll
    for (int nt = 0; nt < 5; ++nt) {
      const bf16x8 bh = *(const bf16x8*)&Bhi[nt * 16 + fr][fk];
      const bf16x8 bl = *(const bf16x8*)&Blo[nt * 16 + fr][fk];
      acc[0][nt] = __builtin_amdgcn_mfma_f32_16x16x32_bf16(a0h, bh, acc[0][nt], 0, 0, 0);
      acc[1][nt] = __builtin_amdgcn_mfma_f32_16x16x32_bf16(a1h, bh, acc[1][nt], 0, 0, 0);
      acc[0][nt] = __builtin_amdgcn_mfma_f32_16x16x32_bf16(a0l, bh, acc[0][nt], 0, 0, 0);
      acc[1][nt] = __builtin_amdgcn_mfma_f32_16x16x32_bf16(a1l, bh, acc[1][nt], 0, 0, 0);
      acc[0][nt] = __builtin_amdgcn_mfma_f32_16x16x32_bf16(a0h, bl, acc[0][nt], 0, 0, 0);
      acc[1][nt] = __builtin_amdgcn_mfma_f32_16x16x32_bf16(a1h, bl, acc[1][nt], 0, 0, 0);
    }
  }

  // ---- epilogue: D col = lane&15, row = (lane>>4)*4 + reg ----
#pragma unroll
  for (int nt = 0; nt < 5; ++nt) {
    const int en = n0 + nt * 16 + fr;
    const float bs = bih[en] + bhh[en];
#pragma unroll
    for (int mt = 0; mt < 2; ++mt) {
      const int emb = m0 + wv * 32 + mt * 16 + (lane >> 4) * 4;
#pragma unroll
      for (int r = 0; r < 4; ++r)
        G[(size_t)(emb + r) * G4H + en] = acc[mt][nt][r] + bs;
    }
  }
}

// ---------------------------------------------------------------------------
// Recurrence: one block (512 thr) per 2 batch elements; 128 blocks.
// FROZEN at R9 (the 3173µs kernel) — do not touch GEMV lane geometry.
// ---------------------------------------------------------------------------
__global__ __launch_bounds__(512, 2) void mann_kernel(
    const float* __restrict__ G, const float* __restrict__ WhhT,
    const float* __restrict__ WrhT, const float* __restrict__ WkaT,
    const float* __restrict__ bka, const float* __restrict__ brh,
    const float* __restrict__ Who, const float* __restrict__ bho,
    const float* __restrict__ Wro, const float* __restrict__ bro,
    float* __restrict__ out)
{
  __shared__ __attribute__((aligned(16))) float M_s[NBAT][NN * MST];
  __shared__ __attribute__((aligned(16))) float h2[HH * NBAT];   // [k*2+i]
  __shared__ __attribute__((aligned(16))) float c2[HH * NBAT];
  __shared__ __attribute__((aligned(16))) float r2[RR * DD * NBAT];
  __shared__ __attribute__((aligned(16))) float brh_s[HH];
  __shared__ float wr_s[NBAT][RR * NN];
  __shared__ float ww_s[NBAT][RR * NN];
  __shared__ float wu_s[NBAT][NN];
  __shared__ float Mn2_s[NBAT][NN];
  __shared__ float kn2_s[NBAT][RR];
  __shared__ __attribute__((aligned(16))) float gates_s[NBAT][G4H];
  __shared__ __attribute__((aligned(16))) float ka_s[NBAT][KAW];
  __shared__ __attribute__((aligned(16))) float bka_s[KAW];
  __shared__ __attribute__((aligned(16))) float Gbuf_s[NBAT][G4H];
  __shared__ float Who_s[NCLS * HH], Wro_s[NCLS * RR * DD], bo_s[NCLS];
  __shared__ int   lu_s[NBAT][RR];

  // Aliases into the gates region (temporally disjoint):
  float*  Kp   = &gates_s[0][0];          // [2][512] wr_t (P8..P12)
  float4* pkA4 = (float4*)&gates_s[0][0]; // P1 partials batch0 (50 float4)
  float4* pkB4 = pkA4 + 50;               // P1 partials batch1
  float4* pka4 = (float4*)&gates_s[0][0]; // P4 partials: [0..80]=b0, [81..161]=b1

  const int tid = threadIdx.x;
  const int b0  = blockIdx.x * NBAT;

  // ---- init ----
  for (int e = tid; e < NBAT * NN * MST; e += 512) (&M_s[0][0])[e] = 0.f;
  for (int e = tid; e < NBAT * RR * NN; e += 512) (&wr_s[0][0])[e] = 0.f;
  if (tid < NBAT * NN) (&wu_s[0][0])[tid] = 0.f;
  for (int e = tid; e < HH * NBAT; e += 512) { h2[e] = 0.f; c2[e] = 0.f; }
  if (tid < RR * DD * NBAT) r2[tid] = 0.f;
  if (tid < HH) brh_s[tid] = brh[tid];
  if (tid < KAW) bka_s[tid] = bka[tid];
  for (int e = tid; e < NCLS * HH; e += 512) Who_s[e] = Who[e];
  for (int e = tid; e < NCLS * RR * DD; e += 512) Wro_s[e] = Wro[e];
  if (tid < NCLS) bo_s[tid] = bho[tid] + bro[tid];
  if (tid < NBAT * 200) {
    const int i = tid / 200, o = tid - i * 200;
    ((float4*)&Gbuf_s[i][0])[o] =
        ((const float4*)(G + ((size_t)(b0 + i) * TB) * G4H))[o];
  }
  __syncthreads();

  const int ofs1 = (int)((blockIdx.x * 3u) % 10u);
  const int ofs2 = (int)((blockIdx.x * 7u) % 25u);
  const int ofs4 = (int)((blockIdx.x * 5u) % 25u);

#pragma clang loop unroll(disable)
  for (int t = 0; t < TB; ++t) {
    float4 a0v = make_float4(0.f, 0.f, 0.f, 0.f);
    float4 a1v = make_float4(0.f, 0.f, 0.f, 0.f);

    // ---- P1: h += r @ Wrh^T + brh (100 lanes: 50 j4 x 2 k-halves, dwordx4) ----
    if (tid < 100) {
      const int kh = tid / 50, j4 = tid - kh * 50;
      const int kbeg = kh * 80;
      const float4* __restrict__ Wr4 = (const float4*)WrhT + (size_t)kbeg * 50 + j4;
      float4 w0[8], w1[8], w2[8], w3[8];
#define P1_LOAD(B, CH) { const int mm = (CH) * 8; _Pragma("unroll") \
      for (int u = 0; u < 8; ++u) B[u] = Wr4[(mm + u) * 50]; }
#define P1_FMA(B, CH) { const int kb = kbeg + (CH) * 8; _Pragma("unroll") \
      for (int u = 0; u < 8; ++u) { const float2 rk = *(const float2*)&r2[(kb + u) * 2]; \
        a0v.x += rk.x * B[u].x; a0v.y += rk.x * B[u].y; a0v.z += rk.x * B[u].z; a0v.w += rk.x * B[u].w; \
        a1v.x += rk.y * B[u].x; a1v.y += rk.y * B[u].y; a1v.z += rk.y * B[u].z; a1v.w += rk.y * B[u].w; } }
      PIPE4(10, ofs1, P1_LOAD, P1_FMA)
      if (kh) { pkA4[j4] = a0v; pkB4[j4] = a1v; }
    }
    __syncthreads();
    if (tid < 50) {
      const int j4 = tid;
      const float4 pA = pkA4[j4], pB = pkB4[j4];
      const float4 brv = ((const float4*)brh_s)[j4];
      float4 hv0 = *(const float4*)&h2[8 * j4];
      float4 hv1 = *(const float4*)&h2[8 * j4 + 4];
      hv0.x += brv.x + a0v.x + pA.x;  hv0.y += brv.x + a1v.x + pB.x;
      hv0.z += brv.y + a0v.y + pA.y;  hv0.w += brv.y + a1v.y + pB.y;
      hv1.x += brv.z + a0v.z + pA.z;  hv1.y += brv.z + a1v.z + pB.z;
      hv1.z += brv.w + a0v.w + pA.w;  hv1.w += brv.w + a1v.w + pB.w;
      *(float4*)&h2[8 * j4]     = hv0;
      *(float4*)&h2[8 * j4 + 4] = hv1;
    }
    __syncthreads();

    // ---- P2: gates = Gbuf + h @ Whh^T (200 lanes x dwordx4, 2 batches) ----
    if (tid < 200) {
      const float4* __restrict__ Wh4 = (const float4*)WhhT + tid;
      float4 g0 = *(const float4*)&Gbuf_s[0][4 * tid];
      float4 g1 = *(const float4*)&Gbuf_s[1][4 * tid];
      float4 w0[8], w1[8], w2[8], w3[8];
#define P2_LOAD(B, CH) { const int kk = (CH) * 8; _Pragma("unroll") \
      for (int u = 0; u < 8; ++u) B[u] = Wh4[(kk + u) * 200]; }
#define P2_FMA(B, CH) { const int kc = (CH) * 8; _Pragma("unroll") \
      for (int u = 0; u < 8; ++u) { const float2 hk = *(const float2*)&h2[(kc + u) * 2]; \
        g0.x += hk.x * B[u].x; g0.y += hk.x * B[u].y; g0.z += hk.x * B[u].z; g0.w += hk.x * B[u].w; \
        g1.x += hk.y * B[u].x; g1.y += hk.y * B[u].y; g1.z += hk.y * B[u].z; g1.w += hk.y * B[u].w; } }
      PIPE4(25, ofs2, P2_LOAD, P2_FMA)
      *(float4*)&gates_s[0][4 * tid] = g0;
      *(float4*)&gates_s[1][4 * tid] = g1;
    }
    __syncthreads();

    // ---- P3: LSTM pointwise (400 items) ----
    if (tid < NBAT * HH) {
      const int i = tid / HH, k = tid - i * HH;
      const float ig = sigmoidf_(gates_s[i][k]);
      const float fg = sigmoidf_(gates_s[i][HH + k]);
      const float gg = tanhf(gates_s[i][2 * HH + k]);
      const float og = sigmoidf_(gates_s[i][3 * HH + k]);
      const float cn = fg * c2[k * NBAT + i] + ig * gg;
      c2[k * NBAT + i] = cn;
      h2[k * NBAT + i] = og * tanhf(cn);
    }
    __syncthreads();

    // ---- P4: [key|add|sigma] = bka + h @ Wka^T (162 lanes x dwordx4) ;
    //      lanes>=384 prefetch G(t+1) ----
    float4 kav0 = make_float4(0.f, 0.f, 0.f, 0.f);
    float4 kav1 = make_float4(0.f, 0.f, 0.f, 0.f);
    if (tid < 162) {
      const int kh = tid / 81, j4 = tid - kh * 81;
      const int kbeg = kh * 100;
      const float4* __restrict__ Wk4 = (const float4*)WkaT + (size_t)kbeg * 81 + j4;
      float4 w0[4], w1[4], w2[4], w3[4];
#define P4_LOAD(B, CH) { const int kk = (CH) * 4; _Pragma("unroll") \
      for (int u = 0; u < 4; ++u) B[u] = Wk4[(kk + u) * 81]; }
#define P4_FMA(B, CH) { const int kc = kbeg + (CH) * 4; _Pragma("unroll") \
      for (int u = 0; u < 4; ++u) { const float2 hk = *(const float2*)&h2[(kc + u) * 2]; \
        kav0.x += hk.x * B[u].x; kav0.y += hk.x * B[u].y; kav0.z += hk.x * B[u].z; kav0.w += hk.x * B[u].w; \
        kav1.x += hk.y * B[u].x; kav1.y += hk.y * B[u].y; kav1.z += hk.y * B[u].z; kav1.w += hk.y * B[u].w; } }
      PIPE4(25, ofs4, P4_LOAD, P4_FMA)
      if (kh) { pka4[j4] = kav0; pka4[81 + j4] = kav1; }
    } else if (tid >= 384 && t + 1 < TB) {
      for (int idx = tid - 384; idx < NBAT * 200; idx += 128) {
        const int i = idx / 200, o = idx - i * 200;
        ((float4*)&Gbuf_s[i][0])[o] =
            ((const float4*)(G + ((size_t)(b0 + i) * TB + t + 1) * G4H))[o];
      }
    }
    __syncthreads();
    if (tid < 81) {
      const float4 bbv = ((const float4*)bka_s)[tid];
      const float4 p0 = pka4[tid], p1 = pka4[81 + tid];
      float4 v0, v1;
      v0.x = kav0.x + p0.x + bbv.x; v0.y = kav0.y + p0.y + bbv.y;
      v0.z = kav0.z + p0.z + bbv.z; v0.w = kav0.w + p0.w + bbv.w;
      v1.x = kav1.x + p1.x + bbv.x; v1.y = kav1.y + p1.y + bbv.y;
      v1.z = kav1.z + p1.z + bbv.z; v1.w = kav1.w + p1.w + bbv.w;
      *(float4*)&ka_s[0][4 * tid] = v0;
      *(float4*)&ka_s[1][4 * tid] = v1;
    }
    __syncthreads();

    // ---- P5: least-used select (waves 0-1, one per batch) + key norms ----
    if (tid < NBAT * 64) {
      const int i = tid >> 6, l = tid & 63;
      unsigned u0v = __float_as_uint(wu_s[i][l]);
      unsigned u1v = __float_as_uint(wu_s[i][l + 64]);
      if (u0v == 0x80000000u) u0v = 0u;
      if (u1v == 0x80000000u) u1v = 0u;
      u0v = (u0v & 0x80000000u) ? ~u0v : (u0v | 0x80000000u);
      u1v = (u1v & 0x80000000u) ? ~u1v : (u1v | 0x80000000u);
      unsigned long long k0 = ((unsigned long long)u0v << 32) | (unsigned)l;
      unsigned long long k1 = ((unsigned long long)u1v << 32) | (unsigned)(l + 64);
#pragma unroll
      for (int rsel = 0; rsel < RR; ++rsel) {
        unsigned long long mn = (k0 < k1) ? k0 : k1;
#pragma unroll
        for (int off = 32; off; off >>= 1) {
          const unsigned long long o = __shfl_xor(mn, off);
          if (o < mn) mn = o;
        }
        const int idx = (int)(mn & 0xFFFFFFFFull);
        if (l == 0) lu_s[i][rsel] = idx;
        if (idx == l)      k0 = ~0ull;
        if (idx == l + 64) k1 = ~0ull;
      }
    } else if (tid < NBAT * 64 + NBAT * RR) {
      const int e = tid - NBAT * 64;
      const int i = e >> 2, q = e & 3;
      float s = 0.f;
#pragma unroll
      for (int d4 = 0; d4 < 10; ++d4) {
        const float4 v = *(const float4*)&ka_s[i][q * DD + 4 * d4];
        s += v.x * v.x + v.y * v.y + v.z * v.z + v.w * v.w;
      }
      kn2_s[i][q] = s;
    }
    __syncthreads();

    // ---- P6: ww = sigma*wr + (1-sigma)*wlu ----
    {
      const int n = tid & (NN - 1);
#pragma unroll
      for (int i = 0; i < NBAT; ++i) {
        const float sg = ka_s[i][320];
        const int l0 = lu_s[i][0], l1 = lu_s[i][1], l2 = lu_s[i][2], l3 = lu_s[i][3];
        const float wlu = (n == l0 || n == l1 || n == l2 || n == l3) ? 1.f : 0.f;
        ww_s[i][tid] = sg * wr_s[i][tid] + (1.f - sg) * wlu;
      }
    }
    __syncthreads();

    // ---- P7: M = M*wlu + ww^T @ add ; fused row-norm (256 lanes: i,n) ----
    if (tid < NBAT * NN) {
      const int i = tid >> 7, n = tid & (NN - 1);
      const int l0 = lu_s[i][0], l1 = lu_s[i][1], l2 = lu_s[i][2], l3 = lu_s[i][3];
      const float wlu = (n == l0 || n == l1 || n == l2 || n == l3) ? 1.f : 0.f;
      const float wwv0 = ww_s[i][n],          wwv1 = ww_s[i][NN + n];
      const float wwv2 = ww_s[i][2 * NN + n], wwv3 = ww_s[i][3 * NN + n];
      float* Mr = &M_s[i][n * MST];
      const float* Ad = &ka_s[i][160];
      float mn2 = 0.f;
#pragma unroll
      for (int d4 = 0; d4 < 10; ++d4) {
        float4 m = *(const float4*)&Mr[4 * d4];
        m.x *= wlu; m.y *= wlu; m.z *= wlu; m.w *= wlu;
        const float4 av0 = *(const float4*)&Ad[0 * DD + 4 * d4];
        const float4 av1 = *(const float4*)&Ad[1 * DD + 4 * d4];
        const float4 av2 = *(const float4*)&Ad[2 * DD + 4 * d4];
        const float4 av3 = *(const float4*)&Ad[3 * DD + 4 * d4];
        m.x += wwv0 * av0.x + wwv1 * av1.x + wwv2 * av2.x + wwv3 * av3.x;
        m.y += wwv0 * av0.y + wwv1 * av1.y + wwv2 * av2.y + wwv3 * av3.y;
        m.z += wwv0 * av0.z + wwv1 * av1.z + wwv2 * av2.z + wwv3 * av3.z;
        m.w += wwv0 * av0.w + wwv1 * av1.w + wwv2 * av2.w + wwv3 * av3.w;
        *(float4*)&Mr[4 * d4] = m;
        mn2 += m.x * m.x + m.y * m.y + m.z * m.z + m.w * m.w;
      }
      Mn2_s[i][n] = mn2;
    }
    __syncthreads();

    // ---- P8: K = cosine(key, M): 512 lanes, each reads one M row, 2 keys ----
    {
      const int i = tid >> 8, qq = (tid >> 7) & 1, n = tid & (NN - 1);
      const float* Mr = &M_s[i][n * MST];
      const float* Ky0 = &ka_s[i][qq * DD];
      const float* Ky1 = &ka_s[i][(qq + 2) * DD];
      float s0 = 0.f, s1 = 0.f;
#pragma unroll
      for (int d4 = 0; d4 < 10; ++d4) {
        const float4 mv = *(const float4*)&Mr[4 * d4];
        const float4 k0v = *(const float4*)&Ky0[4 * d4];
        const float4 k1v = *(const float4*)&Ky1[4 * d4];
        s0 += k0v.x * mv.x + k0v.y * mv.y + k0v.z * mv.z + k0v.w * mv.w;
        s1 += k1v.x * mv.x + k1v.y * mv.y + k1v.z * mv.z + k1v.w * mv.w;
      }
      const float mn2 = Mn2_s[i][n];
      Kp[(i << 9) + qq * NN + n]       = s0 / sqrtf(kn2_s[i][qq] * mn2 + 1e-6f);
      Kp[(i << 9) + (qq + 2) * NN + n] = s1 / sqrtf(kn2_s[i][qq + 2] * mn2 + 1e-6f);
    }
    __syncthreads();

    // ---- P9: softmax over N (8 rows, one per wave) ----
    {
      const int w = tid >> 6, l = tid & 63;
      float* Kr = Kp + ((w >> 2) << 9) + (w & 3) * NN;
      const float v0 = Kr[l], v1 = Kr[l + 64];
      float mx = fmaxf(v0, v1);
#pragma unroll
      for (int off = 32; off; off >>= 1) mx = fmaxf(mx, __shfl_xor(mx, off));
      const float e0 = expf(v0 - mx), e1 = expf(v1 - mx);
      float s = e0 + e1;
#pragma unroll
      for (int off = 32; off; off >>= 1) s += __shfl_xor(s, off);
      const float inv = 1.f / s;
      Kr[l] = e0 * inv; Kr[l + 64] = e1 * inv;
    }
    __syncthreads();

    // ---- P10: r = wr_t @ M (80 lanes, broadcast) ; P11: wu (lanes 256+) ----
    if (tid < NBAT * RR * 10) {
      const int i = tid / (RR * 10), rem = tid - i * (RR * 10);
      const int q = rem / 10, d4 = rem - q * 10;
      const float* Kr = Kp + (i << 9) + q * NN;
      const float* Mb = &M_s[i][4 * d4];
      float4 acc = make_float4(0.f, 0.f, 0.f, 0.f);
      for (int n = 0; n < NN; ++n) {
        const float kw = Kr[n];
        const float4 mv = *(const float4*)&Mb[n * MST];
        acc.x += kw * mv.x; acc.y += kw * mv.y;
        acc.z += kw * mv.z; acc.w += kw * mv.w;
      }
      const int dbase = (q * DD + 4 * d4) * NBAT + i;
      r2[dbase]            = acc.x;
      r2[dbase + NBAT]     = acc.y;
      r2[dbase + 2 * NBAT] = acc.z;
      r2[dbase + 3 * NBAT] = acc.w;
    } else if (tid >= 256 && tid < 256 + NBAT * NN) {
      const int e = tid - 256;
      const int i = e >> 7, n = e & (NN - 1);
      float s = 0.95f * wu_s[i][n];
#pragma unroll
      for (int q = 0; q < RR; ++q)
        s += Kp[(i << 9) + q * NN + n] + ww_s[i][q * NN + n];
      wu_s[i][n] = s;
    }
    __syncthreads();

    // ---- P12: out (waves 0-1) ; wr <- wr_t (waves 4-7) ----
    if (tid < NBAT * 64) {
      const int i = tid >> 6, l = tid & 63;
      const size_t ob = ((size_t)(b0 + i) * TB + t) * NCLS;
#pragma unroll
      for (int j = 0; j < NCLS; ++j) {
        float p = 0.f;
        for (int k = l; k < HH; k += 64)      p += h2[k * NBAT + i] * Who_s[j * HH + k];
        for (int m = l; m < RR * DD; m += 64) p += r2[m * NBAT + i] * Wro_s[j * RR * DD + m];
#pragma unroll
        for (int off = 32; off; off >>= 1) p += __shfl_xor(p, off);
        if (l == 0) out[ob + j] = p + bo_s[j];
      }
    } else if (tid >= 256) {
      for (int f = tid - 256; f < NBAT * RR * NN; f += 256) (&wr_s[0][0])[f] = Kp[f];
    }
    __syncthreads();
  }
}

// ---------------------------------------------------------------------------
extern "C" void kernel_launch(void* const* d_in, const int* in_sizes, int n_in,
                              void* d_out, int out_size, void* d_ws, size_t ws_size,
                              hipStream_t stream) {
  const float* x    = (const float*)d_in[0];
  const float* Wkey = (const float*)d_in[1];
  const float* bkey = (const float*)d_in[2];
  const float* Wadd = (const float*)d_in[3];
  const float* badd = (const float*)d_in[4];
  const float* Wsig = (const float*)d_in[5];
  const float* bsig = (const float*)d_in[6];
  const float* Who  = (const float*)d_in[7];
  const float* bho  = (const float*)d_in[8];
  const float* Wro  = (const float*)d_in[9];
  const float* bro  = (const float*)d_in[10];
  const float* Wrh  = (const float*)d_in[11];
  const float* brh  = (const float*)d_in[12];
  const float* Wih  = (const float*)d_in[13];
  const float* bih  = (const float*)d_in[14];
  const float* Whh  = (const float*)d_in[15];
  const float* bhh  = (const float*)d_in[16];

  float* ws   = (float*)d_ws;
  float* G    = ws;                       // 25600*800
  float* WhhT = G + (size_t)25600 * 800;  // 160,000
  float* WrhT = WhhT + 160000;            // 32,000
  float* WkaT = WrhT + 32000;             // 64,800
  float* bka  = WkaT + 64800;             // 324

  prep_kernel<<<(160000 + 255) / 256, 256, 0, stream>>>(
      Whh, Wrh, Wkey, Wadd, Wsig, bkey, badd, bsig, WhhT, WrhT, WkaT, bka);

  dim3 gA(G4H / GN, 25600 / GM);   // (10, 200)
  gemm_in2_kernel<<<gA, 256, 0, stream>>>(x, Wih, bih, bhh, G);

  mann_kernel<<<NBLK, 512, 0, stream>>>(G, WhhT, WrhT, WkaT, bka, brh,
                                        Who, bho, Wro, bro, (float*)d_out);
}